// Round 9
// baseline (229.569 us; speedup 1.0000x reference)
//
#include <hip/hip_runtime.h>
#include <math.h>

#define BB 16
#define SS 8192
#define HH 768
#define NH 12
#define HD 64
#define SCALE 0.125f
#define CPB 48            // 768 blocks = 3/CU; chunks: 16x22 + 32x21 tiles of 8 rows

// ws float offsets
#define WS_QKP   0        // 9216
#define WS_C     9216     // 16
#define WS_GATE  9232     // 768
#define WS_OP    10240    // 16*768
#define WS_POOLED 22528   // 16*12*768
#define WS_STATS 169984   // pm[BB*CPB*NH], pl[BB*CPB*NH], part[BB*CPB*NH*HH]

// async global->LDS, 16B per lane; lds dest is wave-uniform base (+lane*16 in HW)
#define GLL(g, l) __builtin_amdgcn_global_load_lds(                      \
    (const __attribute__((address_space(1))) void*)(g),                  \
    (__attribute__((address_space(3))) void*)(l), 16, 0, 0)

// Raw barriers with targeted drains (T3/T4): don't flush vmcnt (in-flight
// global_load_lds prefetch) at the intra-tile barriers; drain it only at the
// end-of-tile barrier, right before the next tile's LDS reads.
#define BAR_LGKM() do {                                        \
    __builtin_amdgcn_sched_barrier(0);                         \
    asm volatile("s_waitcnt lgkmcnt(0)" ::: "memory");         \
    __builtin_amdgcn_sched_barrier(0);                         \
    __builtin_amdgcn_s_barrier();                              \
    __builtin_amdgcn_sched_barrier(0);                         \
} while (0)
#define BAR_ALL() do {                                         \
    __builtin_amdgcn_sched_barrier(0);                         \
    asm volatile("s_waitcnt vmcnt(0) lgkmcnt(0)" ::: "memory");\
    __builtin_amdgcn_sched_barrier(0);                         \
    __builtin_amdgcn_s_barrier();                              \
    __builtin_amdgcn_sched_barrier(0);                         \
} while (0)

__device__ __forceinline__ float dot4(float4 a, float4 b) {
    return a.x * b.x + a.y * b.y + a.z * b.z + a.w * b.w;
}

// DPP rotate-add within 16-lane rows (VALU pipe)
template<int CTRL>
__device__ __forceinline__ float dpp_add(float x) {
    int r = __builtin_amdgcn_update_dpp(0, __float_as_int(x), CTRL, 0xF, 0xF, true);
    return x + __int_as_float(r);
}
__device__ __forceinline__ float sum16(float x) {
    x = dpp_add<0x121>(x);   // row_ror:1
    x = dpp_add<0x122>(x);   // row_ror:2
    x = dpp_add<0x124>(x);   // row_ror:4
    x = dpp_add<0x128>(x);   // row_ror:8
    return x;                // every lane = sum over its 16-lane group
}

// ---------------- K0: qkp = scale*Wk^T q (+c), gate ----------------
__global__ __launch_bounds__(256) void k_pre(const float* __restrict__ query,
                                             const float* __restrict__ w_kv,
                                             const float* __restrict__ b_kv,
                                             const float* __restrict__ w_gate,
                                             const float* __restrict__ b_gate,
                                             float* __restrict__ ws) {
    int blk = blockIdx.x, t = threadIdx.x;
    if (blk < 36) {
        int h = blk / 3;
        int j = (blk % 3) * 256 + t;
        float acc = 0.f;
        #pragma unroll 8
        for (int d = 0; d < HD; d++)
            acc += query[h * HD + d] * w_kv[(size_t)(h * HD + d) * HH + j];
        ws[WS_QKP + h * HH + j] = acc * SCALE;
    } else if (blk == 36) {
        if (t < NH) {
            float acc = 0.f;
            for (int d = 0; d < HD; d++)
                acc += query[t * HD + d] * b_kv[t * HD + d];
            ws[WS_C + t] = acc * SCALE;
        }
    } else {
        // gate: 96 blocks, 8 rows each (2 per wave)
        __shared__ __align__(16) float qs[HH];
        for (int i = t; i < HH; i += 256) qs[i] = query[i];
        __syncthreads();
        int base = (blk - 37) * 8;
        int wave = t >> 6, lane = t & 63;
        #pragma unroll
        for (int o = 0; o < 2; o++) {
            int i = base + wave * 2 + o;
            const float* wr = w_gate + (size_t)i * HH + lane * 4;
            float s = 0.f;
            #pragma unroll
            for (int kk = 0; kk < 3; kk++) {
                float4 wv = *(const float4*)(wr + 256 * kk);
                float4 qv = *(const float4*)&qs[lane * 4 + 256 * kk];
                s += dot4(wv, qv);
            }
            #pragma unroll
            for (int off = 1; off < 64; off <<= 1) s += __shfl_xor(s, off, 64);
            if (lane == 0) {
                float z = s + b_gate[i];
                ws[WS_GATE + i] = 1.0f / (1.0f + expf(-z));
            }
        }
    }
}

// ---------------- K1: fused scores + online softmax + pool ----------------
// Wave w owns heads 3w..3w+2; qkp slices in 36 registers (loaded once).
// 8-row x tiles double-buffered in LDS via global_load_lds (width 16).
// Intra-tile barriers drain LDS only; vmcnt drained once per tile (T3/T4).
__global__ __launch_bounds__(256, 2) void k_fused(const float* __restrict__ x,
                                                  const float* __restrict__ ws,
                                                  float* __restrict__ part,
                                                  float* __restrict__ pm,
                                                  float* __restrict__ pl) {
    __shared__ __align__(16) float xt[2][8 * HH];     // 48 KB
    __shared__ __align__(16) float st16[8 * NH * 4];  // 1.5 KB partials
    __shared__ __align__(16) float wt[8 * NH];
    __shared__ float msh[NH], fsh[NH], lsh[NH], csh[NH];

    int t = threadIdx.x;
    int cblk = blockIdx.x, b = blockIdx.y;
    int wave = t >> 6, lane = t & 63;

    // qkp for this wave's 3 heads at this lane's fixed col slice -> registers
    float4 qr[3][3];
    #pragma unroll
    for (int j = 0; j < 3; j++)
        #pragma unroll
        for (int c2 = 0; c2 < 3; c2++)
            qr[j][c2] = *(const float4*)(ws + WS_QKP + (3 * wave + j) * HH + 4 * lane + 256 * c2);
    if (t < NH) { csh[t] = ws[WS_C + t]; msh[t] = -1e30f; lsh[t] = 0.f; }

    float P[NH][3];
    #pragma unroll
    for (int h = 0; h < NH; h++) { P[h][0] = 0.f; P[h][1] = 0.f; P[h][2] = 0.f; }

    int nt    = (cblk < 16) ? 22 : 21;
    int tile0 = (cblk < 16) ? cblk * 22 : 352 + (cblk - 16) * 21;
    const float* xb = x + ((size_t)b * SS + (size_t)tile0 * 8) * HH;

    // prologue: stage tile 0 -> buf 0 (each wave stages its 2 rows)
    {
        const float* g = xb + (size_t)(2 * wave) * HH + 4 * lane;
        float* l = &xt[0][(2 * wave) * HH];
        GLL(g, l);            GLL(g + 256, l + 256);           GLL(g + 512, l + 512);
        GLL(g + HH, l + HH);  GLL(g + HH + 256, l + HH + 256); GLL(g + HH + 512, l + HH + 512);
    }
    __syncthreads();   // full drain -> tile 0 resident

    for (int tile = 0; tile < nt; tile++) {
        int cur = tile & 1;
        // stage tile+1 into the other buffer; drains at end-of-tile BAR_ALL
        if (tile + 1 < nt) {
            const float* g = xb + ((size_t)(tile + 1) * 8 + 2 * wave) * HH + 4 * lane;
            float* l = &xt[cur ^ 1][(2 * wave) * HH];
            GLL(g, l);            GLL(g + 256, l + 256);           GLL(g + 512, l + 512);
            GLL(g + HH, l + HH);  GLL(g + HH + 256, l + HH + 256); GLL(g + HH + 512, l + HH + 512);
        }
        const float* xc = xt[cur];

        // ---- scores: 3 heads x 8 rows per wave; qkp from regs, x from LDS ----
        #pragma unroll
        for (int r = 0; r < 8; r++) {
            float4 x0 = *(const float4*)&xc[r * HH + 4 * lane];
            float4 x1 = *(const float4*)&xc[r * HH + 4 * lane + 256];
            float4 x2 = *(const float4*)&xc[r * HH + 4 * lane + 512];
            float s0 = dot4(x0, qr[0][0]) + dot4(x1, qr[0][1]) + dot4(x2, qr[0][2]);
            float s1 = dot4(x0, qr[1][0]) + dot4(x1, qr[1][1]) + dot4(x2, qr[1][2]);
            float s2 = dot4(x0, qr[2][0]) + dot4(x1, qr[2][1]) + dot4(x2, qr[2][2]);
            s0 = sum16(s0); s1 = sum16(s1); s2 = sum16(s2);
            if ((lane & 15) == 0) {
                int p = lane >> 4;
                st16[(r * NH + 3 * wave + 0) * 4 + p] = s0;
                st16[(r * NH + 3 * wave + 1) * 4 + p] = s1;
                st16[(r * NH + 3 * wave + 2) * 4 + p] = s2;
            }
        }
        BAR_LGKM();   // st16 visible; staged GLLs stay in flight

        // ---- stats: 96 threads; combine 4 partials, online softmax update ----
        if (t < 96) {
            int rr = t & 7, hh = t >> 3;
            float4 p4 = *(const float4*)&st16[(rr * NH + hh) * 4];
            float v = (p4.x + p4.y) + (p4.z + p4.w) + csh[hh];
            float m8 = v;
            m8 = fmaxf(m8, __shfl_xor(m8, 1, 64));
            m8 = fmaxf(m8, __shfl_xor(m8, 2, 64));
            m8 = fmaxf(m8, __shfl_xor(m8, 4, 64));
            float mo = msh[hh];
            float mn = fmaxf(mo, m8);
            float f  = __expf(mo - mn);
            float w  = __expf(v - mn);
            wt[rr * NH + hh] = w;
            float sm = w;
            sm += __shfl_xor(sm, 1, 64);
            sm += __shfl_xor(sm, 2, 64);
            sm += __shfl_xor(sm, 4, 64);
            if (rr == 0) { msh[hh] = mn; fsh[hh] = f; lsh[hh] = lsh[hh] * f + sm; }
        }
        BAR_LGKM();   // wt/fsh visible; staged GLLs still in flight

        // ---- phase 2: rescale P; pool from LDS tile ----
        #pragma unroll
        for (int h = 0; h < NH; h++) {
            float fh = fsh[h];
            P[h][0] *= fh; P[h][1] *= fh; P[h][2] *= fh;
        }
        #pragma unroll
        for (int r = 0; r < 8; r++) {
            float4 w0 = *(const float4*)&wt[r * NH + 0];
            float4 w4 = *(const float4*)&wt[r * NH + 4];
            float4 w8 = *(const float4*)&wt[r * NH + 8];
            float x0 = xc[r * HH + t];
            float x1 = xc[r * HH + 256 + t];
            float x2 = xc[r * HH + 512 + t];
            P[0][0]  += w0.x * x0;  P[0][1]  += w0.x * x1;  P[0][2]  += w0.x * x2;
            P[1][0]  += w0.y * x0;  P[1][1]  += w0.y * x1;  P[1][2]  += w0.y * x2;
            P[2][0]  += w0.z * x0;  P[2][1]  += w0.z * x1;  P[2][2]  += w0.z * x2;
            P[3][0]  += w0.w * x0;  P[3][1]  += w0.w * x1;  P[3][2]  += w0.w * x2;
            P[4][0]  += w4.x * x0;  P[4][1]  += w4.x * x1;  P[4][2]  += w4.x * x2;
            P[5][0]  += w4.y * x0;  P[5][1]  += w4.y * x1;  P[5][2]  += w4.y * x2;
            P[6][0]  += w4.z * x0;  P[6][1]  += w4.z * x1;  P[6][2]  += w4.z * x2;
            P[7][0]  += w4.w * x0;  P[7][1]  += w4.w * x1;  P[7][2]  += w4.w * x2;
            P[8][0]  += w8.x * x0;  P[8][1]  += w8.x * x1;  P[8][2]  += w8.x * x2;
            P[9][0]  += w8.y * x0;  P[9][1]  += w8.y * x1;  P[9][2]  += w8.y * x2;
            P[10][0] += w8.z * x0;  P[10][1] += w8.z * x1;  P[10][2] += w8.z * x2;
            P[11][0] += w8.w * x0;  P[11][1] += w8.w * x1;  P[11][2] += w8.w * x2;
        }
        BAR_ALL();    // staged tile landed; xc free for next stage
    }

    // write partials
    size_t blkc = (size_t)b * CPB + cblk;
    #pragma unroll
    for (int h = 0; h < NH; h++) {
        part[(blkc * NH + h) * HH + 0 * 256 + t] = P[h][0];
        part[(blkc * NH + h) * HH + 1 * 256 + t] = P[h][1];
        part[(blkc * NH + h) * HH + 2 * 256 + t] = P[h][2];
    }
    if (t < NH) { pm[blkc * NH + t] = msh[t]; pl[blkc * NH + t] = lsh[t]; }
}

// ---------------- K2: combine chunk partials -> pooled ----------------
__global__ __launch_bounds__(256) void k_comb(const float* __restrict__ part,
                                              const float* __restrict__ pm,
                                              const float* __restrict__ pl,
                                              float* __restrict__ pooled) {
    int h = blockIdx.x, b = blockIdx.y, t = threadIdx.x;
    __shared__ float fac[64];
    __shared__ float Ish;
    float mval = -1e30f, lval = 0.f;
    if (t < CPB) {
        mval = pm[((size_t)b * CPB + t) * NH + h];
        lval = pl[((size_t)b * CPB + t) * NH + h];
    }
    if (t < 64) {
        float m = mval;
        #pragma unroll
        for (int off = 1; off < 64; off <<= 1) m = fmaxf(m, __shfl_xor(m, off, 64));
        float fc = (t < CPB) ? __expf(mval - m) : 0.f;
        fac[t] = fc;
        float l = lval * fc;
        #pragma unroll
        for (int off = 1; off < 64; off <<= 1) l += __shfl_xor(l, off, 64);
        if (t == 0) Ish = 1.0f / l;
    }
    __syncthreads();
    float inv = Ish;
    #pragma unroll
    for (int kk = 0; kk < 3; kk++) {
        int col = kk * 256 + t;
        float s = 0.f;
        #pragma unroll 8
        for (int c = 0; c < CPB; c++)
            s += part[(((size_t)b * CPB + c) * NH + h) * HH + col] * fac[c];
        pooled[((size_t)b * NH + h) * HH + col] = s * inv;
    }
}

// ---------------- K3: op = W_v pooled + b_v ----------------
__global__ __launch_bounds__(256) void k_v(const float* __restrict__ pooled,
                                           const float* __restrict__ w_kv,
                                           const float* __restrict__ b_kv,
                                           float* __restrict__ op) {
    int seg = blockIdx.x, b = blockIdx.y, t = threadIdx.x;
    __shared__ __align__(16) float pv[1536];
    for (int i = t; i < 1536; i += 256)
        pv[i] = pooled[((size_t)b * NH + seg * 2) * HH + i];
    __syncthreads();
    int wave = t >> 6, lane = t & 63;
    int lh = wave >> 1;
    for (int o = 0; o < 32; o++) {
        int hd = seg * 128 + wave * 32 + o;
        const float* wr = w_kv + (size_t)(HH + hd) * HH + lane * 4;
        float s = 0.f;
        #pragma unroll
        for (int kk = 0; kk < 3; kk++) {
            float4 wv = *(const float4*)(wr + 256 * kk);
            float4 qv = *(const float4*)&pv[lh * HH + lane * 4 + 256 * kk];
            s += dot4(wv, qv);
        }
        #pragma unroll
        for (int off = 1; off < 64; off <<= 1) s += __shfl_xor(s, off, 64);
        if (lane == 0) op[(size_t)b * HH + hd] = s + b_kv[HH + hd];
    }
}

// ---------------- K4: out = gate * (W_out op + b_out) ----------------
__global__ __launch_bounds__(256) void k_fin(const float* __restrict__ op_in,
                                             const float* __restrict__ w_out,
                                             const float* __restrict__ b_out,
                                             const float* __restrict__ gate,
                                             float* __restrict__ out) {
    int seg = blockIdx.x, b = blockIdx.y, t = threadIdx.x;
    __shared__ __align__(16) float ov[HH];
    for (int i = t; i < HH; i += 256) ov[i] = op_in[(size_t)b * HH + i];
    __syncthreads();
    int wave = t >> 6, lane = t & 63;
    for (int o = 0; o < 32; o++) {
        int i = seg * 128 + wave * 32 + o;
        const float* wr = w_out + (size_t)i * HH + lane * 4;
        float s = 0.f;
        #pragma unroll
        for (int kk = 0; kk < 3; kk++) {
            float4 wv = *(const float4*)(wr + 256 * kk);
            float4 qv = *(const float4*)&ov[lane * 4 + 256 * kk];
            s += dot4(wv, qv);
        }
        #pragma unroll
        for (int off = 1; off < 64; off <<= 1) s += __shfl_xor(s, off, 64);
        if (lane == 0) out[(size_t)b * HH + i] = gate[i] * (s + b_out[i]);
    }
}

extern "C" void kernel_launch(void* const* d_in, const int* in_sizes, int n_in,
                              void* d_out, int out_size, void* d_ws, size_t ws_size,
                              hipStream_t stream) {
    const float* x      = (const float*)d_in[0];
    const float* query  = (const float*)d_in[1];
    const float* w_kv   = (const float*)d_in[2];
    const float* b_kv   = (const float*)d_in[3];
    const float* w_out  = (const float*)d_in[4];
    const float* b_out  = (const float*)d_in[5];
    const float* w_gate = (const float*)d_in[6];
    const float* b_gate = (const float*)d_in[7];
    float* ws  = (float*)d_ws;
    float* out = (float*)d_out;

    float* gate   = ws + WS_GATE;
    float* opbuf  = ws + WS_OP;
    float* pooled = ws + WS_POOLED;
    float* pm     = ws + WS_STATS;
    float* pl     = pm + (size_t)BB * CPB * NH;
    float* part   = pl + (size_t)BB * CPB * NH;

    k_pre<<<133, 256, 0, stream>>>(query, w_kv, b_kv, w_gate, b_gate, ws);
    k_fused<<<dim3(CPB, BB), 256, 0, stream>>>(x, ws, part, pm, pl);
    k_comb<<<dim3(NH, BB), 256, 0, stream>>>(part, pm, pl, pooled);
    k_v<<<dim3(6, BB), 256, 0, stream>>>(pooled, w_kv, b_kv, opbuf);
    k_fin<<<dim3(6, BB), 256, 0, stream>>>(opbuf, w_out, b_out, gate, out);
}

// Round 10
// 211.067 us; speedup vs baseline: 1.0877x; 1.0877x over previous
//
#include <hip/hip_runtime.h>
#include <math.h>

#define BB 16
#define SS 8192
#define HH 768
#define NH 12
#define HD 64
#define SCALE 0.125f
#define CPB 48            // 768 blocks = 3/CU; chunks: 32x43 + 16x42 tiles of 4 rows

// ws float offsets
#define WS_QKP   0        // 9216
#define WS_C     9216     // 16
#define WS_GATE  9232     // 768
#define WS_OP    10240    // 16*768
#define WS_POOLED 22528   // 16*12*768
#define WS_STATS 169984   // pm[BB*CPB*NH], pl[BB*CPB*NH], part[BB*CPB*NH*HH]

// async global->LDS, 16B per lane; global addr is per-lane, lds dest wave-uniform
#define GLL(g, l) __builtin_amdgcn_global_load_lds(                      \
    (const __attribute__((address_space(1))) void*)(g),                  \
    (__attribute__((address_space(3))) void*)(l), 16, 0, 0)

__device__ __forceinline__ float dot4(float4 a, float4 b) {
    return a.x * b.x + a.y * b.y + a.z * b.z + a.w * b.w;
}

// DPP rotate-add within 16-lane rows (VALU pipe)
template<int CTRL>
__device__ __forceinline__ float dpp_add(float x) {
    int r = __builtin_amdgcn_update_dpp(0, __float_as_int(x), CTRL, 0xF, 0xF, true);
    return x + __int_as_float(r);
}
__device__ __forceinline__ float sum16(float x) {
    x = dpp_add<0x121>(x);   // row_ror:1
    x = dpp_add<0x122>(x);   // row_ror:2
    x = dpp_add<0x124>(x);   // row_ror:4
    x = dpp_add<0x128>(x);   // row_ror:8
    return x;                // every lane = sum over its 16-lane group
}

// ---------------- K0: qkp = scale*Wk^T q (+c), gate ----------------
__global__ __launch_bounds__(256) void k_pre(const float* __restrict__ query,
                                             const float* __restrict__ w_kv,
                                             const float* __restrict__ b_kv,
                                             const float* __restrict__ w_gate,
                                             const float* __restrict__ b_gate,
                                             float* __restrict__ ws) {
    int blk = blockIdx.x, t = threadIdx.x;
    if (blk < 36) {
        int h = blk / 3;
        int j = (blk % 3) * 256 + t;
        float acc = 0.f;
        #pragma unroll 8
        for (int d = 0; d < HD; d++)
            acc += query[h * HD + d] * w_kv[(size_t)(h * HD + d) * HH + j];
        ws[WS_QKP + h * HH + j] = acc * SCALE;
    } else if (blk == 36) {
        if (t < NH) {
            float acc = 0.f;
            for (int d = 0; d < HD; d++)
                acc += query[t * HD + d] * b_kv[t * HD + d];
            ws[WS_C + t] = acc * SCALE;
        }
    } else {
        // gate: 96 blocks, 8 rows each (2 per wave)
        __shared__ __align__(16) float qs[HH];
        for (int i = t; i < HH; i += 256) qs[i] = query[i];
        __syncthreads();
        int base = (blk - 37) * 8;
        int wave = t >> 6, lane = t & 63;
        #pragma unroll
        for (int o = 0; o < 2; o++) {
            int i = base + wave * 2 + o;
            const float* wr = w_gate + (size_t)i * HH + lane * 4;
            float s = 0.f;
            #pragma unroll
            for (int kk = 0; kk < 3; kk++) {
                float4 wv = *(const float4*)(wr + 256 * kk);
                float4 qv = *(const float4*)&qs[lane * 4 + 256 * kk];
                s += dot4(wv, qv);
            }
            #pragma unroll
            for (int off = 1; off < 64; off <<= 1) s += __shfl_xor(s, off, 64);
            if (lane == 0) {
                float z = s + b_gate[i];
                ws[WS_GATE + i] = 1.0f / (1.0f + expf(-z));
            }
        }
    }
}

// ---------------- K1: fused scores + online softmax + pool ----------------
// Wave w owns heads 3w..3w+2 end-to-end: qkp in 36 regs, scores reduced
// in-wave (DPP+shfl), online m/l in regs, pool from a 4-row register stash.
// ONE barrier per tile; 4-row tile double-buffered in LDS via global_load_lds.
__global__ __launch_bounds__(256, 2) void k_fused(const float* __restrict__ x,
                                                  const float* __restrict__ ws,
                                                  float* __restrict__ part,
                                                  float* __restrict__ pm,
                                                  float* __restrict__ pl) {
    __shared__ __align__(16) float xt[2][4 * HH];     // 24.6 KB

    int t = threadIdx.x;
    int cblk = blockIdx.x, b = blockIdx.y;
    int wave = t >> 6, lane = t & 63;

    // qkp for this wave's 3 heads at this lane's fixed col slice -> registers
    float4 qr[3][3];
    #pragma unroll
    for (int j = 0; j < 3; j++)
        #pragma unroll
        for (int c2 = 0; c2 < 3; c2++)
            qr[j][c2] = *(const float4*)(ws + WS_QKP + (3 * wave + j) * HH + 4 * lane + 256 * c2);
    float cr[3];
    #pragma unroll
    for (int j = 0; j < 3; j++) cr[j] = ws[WS_C + 3 * wave + j];

    float P[3][12];
    #pragma unroll
    for (int j = 0; j < 3; j++)
        #pragma unroll
        for (int cc = 0; cc < 12; cc++) P[j][cc] = 0.f;
    float m[3] = { -1e30f, -1e30f, -1e30f };
    float l[3] = { 0.f, 0.f, 0.f };

    int nt    = (cblk < 32) ? 43 : 42;
    int tile0 = (cblk < 32) ? cblk * 43 : 1376 + (cblk - 32) * 42;
    const float* xb = x + ((size_t)b * SS + (size_t)tile0 * 4) * HH;

    // prologue: stage tile 0 -> buf 0 (wave w stages row w)
    {
        const float* g = xb + (size_t)wave * HH + 4 * lane;
        float* l0 = &xt[0][wave * HH];
        GLL(g, l0); GLL(g + 256, l0 + 256); GLL(g + 512, l0 + 512);
    }
    __syncthreads();

    for (int tile = 0; tile < nt; tile++) {
        int cur = tile & 1;
        if (tile + 1 < nt) {
            const float* g = xb + ((size_t)(tile + 1) * 4 + wave) * HH + 4 * lane;
            float* ld = &xt[cur ^ 1][wave * HH];
            GLL(g, ld); GLL(g + 256, ld + 256); GLL(g + 512, ld + 512);
        }
        const float* xc = xt[cur];

        // ---- read 4-row tile into register stash ----
        float4 xv[4][3];
        #pragma unroll
        for (int r = 0; r < 4; r++) {
            xv[r][0] = *(const float4*)&xc[r * HH + 4 * lane];
            xv[r][1] = *(const float4*)&xc[r * HH + 4 * lane + 256];
            xv[r][2] = *(const float4*)&xc[r * HH + 4 * lane + 512];
        }

        // ---- scores: in-wave reduce, no LDS, no barrier ----
        float s[4][3];
        #pragma unroll
        for (int r = 0; r < 4; r++) {
            #pragma unroll
            for (int j = 0; j < 3; j++) {
                float a = dot4(xv[r][0], qr[j][0]) + dot4(xv[r][1], qr[j][1])
                        + dot4(xv[r][2], qr[j][2]);
                a = sum16(a);
                a += __shfl_xor(a, 16, 64);
                a += __shfl_xor(a, 32, 64);
                s[r][j] = a + cr[j];
            }
        }

        // ---- online softmax + pool from stash (rescale folded into FMA) ----
        #pragma unroll
        for (int j = 0; j < 3; j++) {
            float tm = fmaxf(fmaxf(s[0][j], s[1][j]), fmaxf(s[2][j], s[3][j]));
            float mn = fmaxf(m[j], tm);
            float f  = __expf(m[j] - mn);
            m[j] = mn;
            float w0 = __expf(s[0][j] - mn);
            float w1 = __expf(s[1][j] - mn);
            float w2 = __expf(s[2][j] - mn);
            float w3 = __expf(s[3][j] - mn);
            l[j] = l[j] * f + ((w0 + w1) + (w2 + w3));
            #pragma unroll
            for (int k = 0; k < 3; k++) {
                P[j][4*k+0] = P[j][4*k+0] * f + w0 * xv[0][k].x + w1 * xv[1][k].x + w2 * xv[2][k].x + w3 * xv[3][k].x;
                P[j][4*k+1] = P[j][4*k+1] * f + w0 * xv[0][k].y + w1 * xv[1][k].y + w2 * xv[2][k].y + w3 * xv[3][k].y;
                P[j][4*k+2] = P[j][4*k+2] * f + w0 * xv[0][k].z + w1 * xv[1][k].z + w2 * xv[2][k].z + w3 * xv[3][k].z;
                P[j][4*k+3] = P[j][4*k+3] * f + w0 * xv[0][k].w + w1 * xv[1][k].w + w2 * xv[2][k].w + w3 * xv[3][k].w;
            }
        }

        __syncthreads();   // staged tile landed; cur free for next stage
    }

    // write partials: head 3w+j, cols 4*lane + 256*k (+0..3)
    size_t blkc = (size_t)b * CPB + cblk;
    #pragma unroll
    for (int j = 0; j < 3; j++) {
        #pragma unroll
        for (int k = 0; k < 3; k++) {
            float4 v = make_float4(P[j][4*k+0], P[j][4*k+1], P[j][4*k+2], P[j][4*k+3]);
            *(float4*)&part[(blkc * NH + 3 * wave + j) * HH + 256 * k + 4 * lane] = v;
        }
        if (lane == 0) {
            pm[blkc * NH + 3 * wave + j] = m[j];
            pl[blkc * NH + 3 * wave + j] = l[j];
        }
    }
}

// ---------------- K2: combine chunk partials -> pooled ----------------
__global__ __launch_bounds__(256) void k_comb(const float* __restrict__ part,
                                              const float* __restrict__ pm,
                                              const float* __restrict__ pl,
                                              float* __restrict__ pooled) {
    int h = blockIdx.x, b = blockIdx.y, t = threadIdx.x;
    __shared__ float fac[64];
    __shared__ float Ish;
    float mval = -1e30f, lval = 0.f;
    if (t < CPB) {
        mval = pm[((size_t)b * CPB + t) * NH + h];
        lval = pl[((size_t)b * CPB + t) * NH + h];
    }
    if (t < 64) {
        float m = mval;
        #pragma unroll
        for (int off = 1; off < 64; off <<= 1) m = fmaxf(m, __shfl_xor(m, off, 64));
        float fc = (t < CPB) ? __expf(mval - m) : 0.f;
        fac[t] = fc;
        float l = lval * fc;
        #pragma unroll
        for (int off = 1; off < 64; off <<= 1) l += __shfl_xor(l, off, 64);
        if (t == 0) Ish = 1.0f / l;
    }
    __syncthreads();
    float inv = Ish;
    #pragma unroll
    for (int kk = 0; kk < 3; kk++) {
        int col = kk * 256 + t;
        float s = 0.f;
        #pragma unroll 8
        for (int c = 0; c < CPB; c++)
            s += part[(((size_t)b * CPB + c) * NH + h) * HH + col] * fac[c];
        pooled[((size_t)b * NH + h) * HH + col] = s * inv;
    }
}

// ---------------- K3: op = W_v pooled + b_v ----------------
__global__ __launch_bounds__(256) void k_v(const float* __restrict__ pooled,
                                           const float* __restrict__ w_kv,
                                           const float* __restrict__ b_kv,
                                           float* __restrict__ op) {
    int seg = blockIdx.x, b = blockIdx.y, t = threadIdx.x;
    __shared__ __align__(16) float pv[1536];
    for (int i = t; i < 1536; i += 256)
        pv[i] = pooled[((size_t)b * NH + seg * 2) * HH + i];
    __syncthreads();
    int wave = t >> 6, lane = t & 63;
    int lh = wave >> 1;
    for (int o = 0; o < 32; o++) {
        int hd = seg * 128 + wave * 32 + o;
        const float* wr = w_kv + (size_t)(HH + hd) * HH + lane * 4;
        float s = 0.f;
        #pragma unroll
        for (int kk = 0; kk < 3; kk++) {
            float4 wv = *(const float4*)(wr + 256 * kk);
            float4 qv = *(const float4*)&pv[lh * HH + lane * 4 + 256 * kk];
            s += dot4(wv, qv);
        }
        #pragma unroll
        for (int off = 1; off < 64; off <<= 1) s += __shfl_xor(s, off, 64);
        if (lane == 0) op[(size_t)b * HH + hd] = s + b_kv[HH + hd];
    }
}

// ---------------- K4: out = gate * (W_out op + b_out) ----------------
__global__ __launch_bounds__(256) void k_fin(const float* __restrict__ op_in,
                                             const float* __restrict__ w_out,
                                             const float* __restrict__ b_out,
                                             const float* __restrict__ gate,
                                             float* __restrict__ out) {
    int seg = blockIdx.x, b = blockIdx.y, t = threadIdx.x;
    __shared__ __align__(16) float ov[HH];
    for (int i = t; i < HH; i += 256) ov[i] = op_in[(size_t)b * HH + i];
    __syncthreads();
    int wave = t >> 6, lane = t & 63;
    for (int o = 0; o < 32; o++) {
        int i = seg * 128 + wave * 32 + o;
        const float* wr = w_out + (size_t)i * HH + lane * 4;
        float s = 0.f;
        #pragma unroll
        for (int kk = 0; kk < 3; kk++) {
            float4 wv = *(const float4*)(wr + 256 * kk);
            float4 qv = *(const float4*)&ov[lane * 4 + 256 * kk];
            s += dot4(wv, qv);
        }
        #pragma unroll
        for (int off = 1; off < 64; off <<= 1) s += __shfl_xor(s, off, 64);
        if (lane == 0) out[(size_t)b * HH + i] = gate[i] * (s + b_out[i]);
    }
}

extern "C" void kernel_launch(void* const* d_in, const int* in_sizes, int n_in,
                              void* d_out, int out_size, void* d_ws, size_t ws_size,
                              hipStream_t stream) {
    const float* x      = (const float*)d_in[0];
    const float* query  = (const float*)d_in[1];
    const float* w_kv   = (const float*)d_in[2];
    const float* b_kv   = (const float*)d_in[3];
    const float* w_out  = (const float*)d_in[4];
    const float* b_out  = (const float*)d_in[5];
    const float* w_gate = (const float*)d_in[6];
    const float* b_gate = (const float*)d_in[7];
    float* ws  = (float*)d_ws;
    float* out = (float*)d_out;

    float* gate   = ws + WS_GATE;
    float* opbuf  = ws + WS_OP;
    float* pooled = ws + WS_POOLED;
    float* pm     = ws + WS_STATS;
    float* pl     = pm + (size_t)BB * CPB * NH;
    float* part   = pl + (size_t)BB * CPB * NH;

    k_pre<<<133, 256, 0, stream>>>(query, w_kv, b_kv, w_gate, b_gate, ws);
    k_fused<<<dim3(CPB, BB), 256, 0, stream>>>(x, ws, part, pm, pl);
    k_comb<<<dim3(NH, BB), 256, 0, stream>>>(part, pm, pl, pooled);
    k_v<<<dim3(6, BB), 256, 0, stream>>>(pooled, w_kv, b_kv, opbuf);
    k_fin<<<dim3(6, BB), 256, 0, stream>>>(opbuf, w_out, b_out, gate, out);
}

// Round 12
// 181.918 us; speedup vs baseline: 1.2619x; 1.1602x over previous
//
#include <hip/hip_runtime.h>
#include <math.h>

#define BB 16
#define SS 8192
#define HH 768
#define NH 12
#define HD 64
#define SCALE 0.125f
#define CPB 48            // 768 blocks = 3/CU; 32 chunks x 43 tiles + 16 x 42 (4-row tiles)

// ws float offsets
#define WS_QKP   0        // 9216
#define WS_C     9216     // 16
#define WS_GATE  9232     // 768
#define WS_OP    10240    // 16*768
#define WS_POOLED 22528   // 16*12*768
#define WS_STATS 169984   // pm[BB*CPB*NH], pl[BB*CPB*NH], part[BB*CPB*NH*HH]

// async global->LDS, 16B per lane; global addr per-lane, lds dest wave-uniform
#define GLL(g, l) __builtin_amdgcn_global_load_lds(                      \
    (const __attribute__((address_space(1))) void*)(g),                  \
    (__attribute__((address_space(3))) void*)(l), 16, 0, 0)

__device__ __forceinline__ float dot4(float4 a, float4 b) {
    return a.x * b.x + a.y * b.y + a.z * b.z + a.w * b.w;
}

// DPP rotate-add within 16-lane rows (VALU pipe)
template<int CTRL>
__device__ __forceinline__ float dpp_add(float x) {
    int r = __builtin_amdgcn_update_dpp(0, __float_as_int(x), CTRL, 0xF, 0xF, true);
    return x + __int_as_float(r);
}

// all-lane sum across 64 lanes: 4 DPP (16-group) + 2 shfl_xor (R10-proven path)
__device__ __forceinline__ float sum64_all(float x) {
    x = dpp_add<0x121>(x);   // row_ror:1
    x = dpp_add<0x122>(x);   // row_ror:2
    x = dpp_add<0x124>(x);   // row_ror:4
    x = dpp_add<0x128>(x);   // row_ror:8  -> every lane = its 16-group sum
    x += __shfl_xor(x, 16, 64);
    x += __shfl_xor(x, 32, 64);
    return x;                // full 64-lane sum, all lanes
}

// ---------------- K0: qkp = scale*Wk^T q (+c), gate ----------------
__global__ __launch_bounds__(256) void k_pre(const float* __restrict__ query,
                                             const float* __restrict__ w_kv,
                                             const float* __restrict__ b_kv,
                                             const float* __restrict__ w_gate,
                                             const float* __restrict__ b_gate,
                                             float* __restrict__ ws) {
    int blk = blockIdx.x, t = threadIdx.x;
    if (blk < 36) {
        int h = blk / 3;
        int j = (blk % 3) * 256 + t;
        float acc = 0.f;
        #pragma unroll 8
        for (int d = 0; d < HD; d++)
            acc += query[h * HD + d] * w_kv[(size_t)(h * HD + d) * HH + j];
        ws[WS_QKP + h * HH + j] = acc * SCALE;
    } else if (blk == 36) {
        if (t < NH) {
            float acc = 0.f;
            for (int d = 0; d < HD; d++)
                acc += query[t * HD + d] * b_kv[t * HD + d];
            ws[WS_C + t] = acc * SCALE;
        }
    } else {
        // gate: 96 blocks, 8 rows each (2 per wave)
        __shared__ __align__(16) float qs[HH];
        for (int i = t; i < HH; i += 256) qs[i] = query[i];
        __syncthreads();
        int base = (blk - 37) * 8;
        int wave = t >> 6, lane = t & 63;
        #pragma unroll
        for (int o = 0; o < 2; o++) {
            int i = base + wave * 2 + o;
            const float* wr = w_gate + (size_t)i * HH + lane * 4;
            float s = 0.f;
            #pragma unroll
            for (int kk = 0; kk < 3; kk++) {
                float4 wv = *(const float4*)(wr + 256 * kk);
                float4 qv = *(const float4*)&qs[lane * 4 + 256 * kk];
                s += dot4(wv, qv);
            }
            #pragma unroll
            for (int off = 1; off < 64; off <<= 1) s += __shfl_xor(s, off, 64);
            if (lane == 0) {
                float z = s + b_gate[i];
                ws[WS_GATE + i] = 1.0f / (1.0f + expf(-z));
            }
        }
    }
}

// ---------------- K1: fused scores + online softmax + pool ----------------
// Wave w owns heads 3w..3w+2 (qkp in 36 regs). 4-row LDS tiles (double-buffered,
// global_load_lds), processed as two 2-row chunks to keep VGPR <= 170
// (12 waves/CU). Scores all-lane-reduced in-wave; defer-max skips rescale.
__global__ __launch_bounds__(256, 3) void k_fused(const float* __restrict__ x,
                                                  const float* __restrict__ ws,
                                                  float* __restrict__ part,
                                                  float* __restrict__ pm,
                                                  float* __restrict__ pl) {
    __shared__ __align__(16) float xt[2][4 * HH];     // 24.6 KB

    int t = threadIdx.x;
    int cblk = blockIdx.x, b = blockIdx.y;
    int wave = t >> 6, lane = t & 63;

    // qkp for this wave's 3 heads at this lane's fixed col slice -> registers
    float4 qr[3][3];
    #pragma unroll
    for (int j = 0; j < 3; j++)
        #pragma unroll
        for (int c2 = 0; c2 < 3; c2++)
            qr[j][c2] = *(const float4*)(ws + WS_QKP + (3 * wave + j) * HH + 4 * lane + 256 * c2);
    float cr[3];
    #pragma unroll
    for (int j = 0; j < 3; j++) cr[j] = ws[WS_C + 3 * wave + j];

    float P[3][12];
    #pragma unroll
    for (int j = 0; j < 3; j++)
        #pragma unroll
        for (int cc = 0; cc < 12; cc++) P[j][cc] = 0.f;
    float m[3] = { -1e30f, -1e30f, -1e30f };
    float l[3] = { 0.f, 0.f, 0.f };

    int nt    = (cblk < 32) ? 43 : 42;
    int tile0 = (cblk < 32) ? cblk * 43 : 1376 + (cblk - 32) * 42;
    const float* xb = x + ((size_t)b * SS + (size_t)tile0 * 4) * HH;

    // prologue: stage tile 0 -> buf 0 (wave w stages row w)
    {
        const float* g = xb + (size_t)wave * HH + 4 * lane;
        float* l0 = &xt[0][wave * HH];
        GLL(g, l0); GLL(g + 256, l0 + 256); GLL(g + 512, l0 + 512);
    }
    __syncthreads();

    for (int tile = 0; tile < nt; tile++) {
        int cur = tile & 1;
        if (tile + 1 < nt) {
            const float* g = xb + ((size_t)(tile + 1) * 4 + wave) * HH + 4 * lane;
            float* ld = &xt[cur ^ 1][wave * HH];
            GLL(g, ld); GLL(g + 256, ld + 256); GLL(g + 512, ld + 512);
        }
        const float* xc = xt[cur];

        // two 2-row chunks: keeps the x stash at 24 VGPRs
        #pragma unroll
        for (int ch = 0; ch < 2; ch++) {
            const float* xr = xc + (2 * ch) * HH;
            float4 xv[2][3];
            #pragma unroll
            for (int r = 0; r < 2; r++) {
                xv[r][0] = *(const float4*)&xr[r * HH + 4 * lane];
                xv[r][1] = *(const float4*)&xr[r * HH + 4 * lane + 256];
                xv[r][2] = *(const float4*)&xr[r * HH + 4 * lane + 512];
            }

            float s[2][3];
            #pragma unroll
            for (int r = 0; r < 2; r++)
                #pragma unroll
                for (int j = 0; j < 3; j++) {
                    float a = dot4(xv[r][0], qr[j][0]) + dot4(xv[r][1], qr[j][1])
                            + dot4(xv[r][2], qr[j][2]);
                    s[r][j] = sum64_all(a) + cr[j];
                }

            // online softmax + pool; rescale only when the max grows (uniform branch)
            #pragma unroll
            for (int j = 0; j < 3; j++) {
                float tm = fmaxf(s[0][j], s[1][j]);
                if (tm > m[j]) {
                    float f = __expf(m[j] - tm);
                    m[j] = tm;
                    l[j] *= f;
                    #pragma unroll
                    for (int cc = 0; cc < 12; cc++) P[j][cc] *= f;
                }
                float w0 = __expf(s[0][j] - m[j]);
                float w1 = __expf(s[1][j] - m[j]);
                l[j] += w0 + w1;
                #pragma unroll
                for (int k = 0; k < 3; k++) {
                    P[j][4*k+0] += w0 * xv[0][k].x + w1 * xv[1][k].x;
                    P[j][4*k+1] += w0 * xv[0][k].y + w1 * xv[1][k].y;
                    P[j][4*k+2] += w0 * xv[0][k].z + w1 * xv[1][k].z;
                    P[j][4*k+3] += w0 * xv[0][k].w + w1 * xv[1][k].w;
                }
            }
        }

        __syncthreads();   // staged tile landed; cur free for next stage
    }

    // write partials: head 3w+j, cols 4*lane + 256*k (+0..3)
    size_t blkc = (size_t)b * CPB + cblk;
    #pragma unroll
    for (int j = 0; j < 3; j++) {
        #pragma unroll
        for (int k = 0; k < 3; k++) {
            float4 v = make_float4(P[j][4*k+0], P[j][4*k+1], P[j][4*k+2], P[j][4*k+3]);
            *(float4*)&part[(blkc * NH + 3 * wave + j) * HH + 256 * k + 4 * lane] = v;
        }
        if (lane == 0) {
            pm[blkc * NH + 3 * wave + j] = m[j];
            pl[blkc * NH + 3 * wave + j] = l[j];
        }
    }
}

// ---------------- K2: combine chunk partials -> pooled ----------------
__global__ __launch_bounds__(256) void k_comb(const float* __restrict__ part,
                                              const float* __restrict__ pm,
                                              const float* __restrict__ pl,
                                              float* __restrict__ pooled) {
    int h = blockIdx.x, b = blockIdx.y, t = threadIdx.x;
    __shared__ float fac[64];
    __shared__ float Ish;
    float mval = -1e30f, lval = 0.f;
    if (t < CPB) {
        mval = pm[((size_t)b * CPB + t) * NH + h];
        lval = pl[((size_t)b * CPB + t) * NH + h];
    }
    if (t < 64) {
        float m = mval;
        #pragma unroll
        for (int off = 1; off < 64; off <<= 1) m = fmaxf(m, __shfl_xor(m, off, 64));
        float fc = (t < CPB) ? __expf(mval - m) : 0.f;
        fac[t] = fc;
        float l = lval * fc;
        #pragma unroll
        for (int off = 1; off < 64; off <<= 1) l += __shfl_xor(l, off, 64);
        if (t == 0) Ish = 1.0f / l;
    }
    __syncthreads();
    float inv = Ish;
    #pragma unroll
    for (int kk = 0; kk < 3; kk++) {
        int col = kk * 256 + t;
        float s = 0.f;
        #pragma unroll 8
        for (int c = 0; c < CPB; c++)
            s += part[(((size_t)b * CPB + c) * NH + h) * HH + col] * fac[c];
        pooled[((size_t)b * NH + h) * HH + col] = s * inv;
    }
}

// ---------------- K3: op = W_v pooled + b_v  (grid 24 x BB, 8 outputs/wave) ----------------
__global__ __launch_bounds__(256) void k_v(const float* __restrict__ pooled,
                                           const float* __restrict__ w_kv,
                                           const float* __restrict__ b_kv,
                                           float* __restrict__ op) {
    int seg = blockIdx.x, b = blockIdx.y, t = threadIdx.x;
    __shared__ __align__(16) float pv[HH];
    int head = seg >> 1;
    for (int i = t; i < HH; i += 256)
        pv[i] = pooled[((size_t)b * NH + head) * HH + i];
    __syncthreads();
    int wave = t >> 6, lane = t & 63;
    #pragma unroll
    for (int o = 0; o < 8; o++) {
        int hd = seg * 32 + wave * 8 + o;
        const float* wr = w_kv + (size_t)(HH + hd) * HH + lane * 4;
        float s = 0.f;
        #pragma unroll
        for (int kk = 0; kk < 3; kk++) {
            float4 wv = *(const float4*)(wr + 256 * kk);
            float4 qv = *(const float4*)&pv[lane * 4 + 256 * kk];
            s += dot4(wv, qv);
        }
        #pragma unroll
        for (int off = 1; off < 64; off <<= 1) s += __shfl_xor(s, off, 64);
        if (lane == 0) op[(size_t)b * HH + hd] = s + b_kv[HH + hd];
    }
}

// ---------------- K4: out = gate * (W_out op + b_out)  (grid 24 x BB) ----------------
__global__ __launch_bounds__(256) void k_fin(const float* __restrict__ op_in,
                                             const float* __restrict__ w_out,
                                             const float* __restrict__ b_out,
                                             const float* __restrict__ gate,
                                             float* __restrict__ out) {
    int seg = blockIdx.x, b = blockIdx.y, t = threadIdx.x;
    __shared__ __align__(16) float ov[HH];
    for (int i = t; i < HH; i += 256) ov[i] = op_in[(size_t)b * HH + i];
    __syncthreads();
    int wave = t >> 6, lane = t & 63;
    #pragma unroll
    for (int o = 0; o < 8; o++) {
        int i = seg * 32 + wave * 8 + o;
        const float* wr = w_out + (size_t)i * HH + lane * 4;
        float s = 0.f;
        #pragma unroll
        for (int kk = 0; kk < 3; kk++) {
            float4 wv = *(const float4*)(wr + 256 * kk);
            float4 qv = *(const float4*)&ov[lane * 4 + 256 * kk];
            s += dot4(wv, qv);
        }
        #pragma unroll
        for (int off = 1; off < 64; off <<= 1) s += __shfl_xor(s, off, 64);
        if (lane == 0) out[(size_t)b * HH + i] = gate[i] * (s + b_out[i]);
    }
}

extern "C" void kernel_launch(void* const* d_in, const int* in_sizes, int n_in,
                              void* d_out, int out_size, void* d_ws, size_t ws_size,
                              hipStream_t stream) {
    const float* x      = (const float*)d_in[0];
    const float* query  = (const float*)d_in[1];
    const float* w_kv   = (const float*)d_in[2];
    const float* b_kv   = (const float*)d_in[3];
    const float* w_out  = (const float*)d_in[4];
    const float* b_out  = (const float*)d_in[5];
    const float* w_gate = (const float*)d_in[6];
    const float* b_gate = (const float*)d_in[7];
    float* ws  = (float*)d_ws;
    float* out = (float*)d_out;

    float* gate   = ws + WS_GATE;
    float* opbuf  = ws + WS_OP;
    float* pooled = ws + WS_POOLED;
    float* pm     = ws + WS_STATS;
    float* pl     = pm + (size_t)BB * CPB * NH;
    float* part   = pl + (size_t)BB * CPB * NH;

    k_pre<<<133, 256, 0, stream>>>(query, w_kv, b_kv, w_gate, b_gate, ws);
    k_fused<<<dim3(CPB, BB), 256, 0, stream>>>(x, ws, part, pm, pl);
    k_comb<<<dim3(NH, BB), 256, 0, stream>>>(part, pm, pl, pooled);
    k_v<<<dim3(24, BB), 256, 0, stream>>>(pooled, w_kv, b_kv, opbuf);
    k_fin<<<dim3(24, BB), 256, 0, stream>>>(opbuf, w_out, b_out, gate, out);
}